// Round 5
// baseline (473.757 us; speedup 1.0000x reference)
//
#include <hip/hip_runtime.h>
#include <cstdint>
#include <cstddef>

#ifndef NEG_SLOPE
#define NEG_SLOPE 0.2f
#endif

// ---------------------------------------------------------------------------
// K0: detect whether edge_index is stored as int64 (low/high int32 pairs) or
// int32. Values are node ids in [0, 50000) so int64 high words are all zero.
// ---------------------------------------------------------------------------
__global__ void detect_kernel(const int* __restrict__ ei, int* __restrict__ flag) {
    if (threadIdx.x == 0 && blockIdx.x == 0) {
        int orv = 0;
#pragma unroll
        for (int k = 0; k < 16; ++k) orv |= ei[2 * k + 1];
        *flag = (orv == 0) ? 1 : 0;
    }
}

// K1: deg[i] = 1 (self loop)
__global__ void init_deg_kernel(int* __restrict__ deg, int n) {
    int i = blockIdx.x * blockDim.x + threadIdx.x;
    if (i < n) deg[i] = 1;
}

// K2: count in-degrees
__global__ void count_kernel(const int* __restrict__ ei, int E,
                             int* __restrict__ deg, const int* __restrict__ flag) {
    int is64 = *flag;
    int stride = gridDim.x * blockDim.x;
    for (int e = blockIdx.x * blockDim.x + threadIdx.x; e < E; e += stride) {
        int dst = is64 ? ei[2 * ((long)E + e)] : ei[E + e];
        atomicAdd(&deg[dst], 1);
    }
}

// K3: exclusive scan deg -> off (single block, wave-scan based)
__global__ __launch_bounds__(1024) void scan_kernel(const int* __restrict__ deg,
                                                    int* __restrict__ off, int n) {
    __shared__ int wsum[16];
    __shared__ int carry_s;
    int t = threadIdx.x;
    int lane = t & 63, wid = t >> 6;
    if (t == 0) carry_s = 0;
    __syncthreads();
    for (int base = 0; base < n; base += 1024) {
        int idx = base + t;
        int v = (idx < n) ? deg[idx] : 0;
        int inc = v;
#pragma unroll
        for (int d = 1; d < 64; d <<= 1) {
            int o = __shfl_up(inc, d, 64);
            if (lane >= d) inc += o;
        }
        if (lane == 63) wsum[wid] = inc;
        __syncthreads();
        int carry = carry_s;
        int wpre = 0;
        for (int w = 0; w < wid; ++w) wpre += wsum[w];
        if (idx < n) off[idx] = carry + wpre + inc - v;
        __syncthreads();
        if (t == 1023) carry_s = carry + wpre + inc;
    }
    __syncthreads();
    if (t == 0) off[n] = carry_s;
}

// K4: place self-loop at the head of each node's bucket, init cursor
__global__ void selfloop_kernel(const int* __restrict__ off, int* __restrict__ cursor,
                                int* __restrict__ csr, int n) {
    int i = blockIdx.x * blockDim.x + threadIdx.x;
    if (i < n) {
        int o = off[i];
        csr[o] = i;
        cursor[i] = o + 1;
    }
}

// K5: scatter edges into CSR buckets (store src id)
__global__ void fill_kernel(const int* __restrict__ ei, int E,
                            int* __restrict__ cursor, int* __restrict__ csr,
                            const int* __restrict__ flag) {
    int is64 = *flag;
    int stride = gridDim.x * blockDim.x;
    for (int e = blockIdx.x * blockDim.x + threadIdx.x; e < E; e += stride) {
        int src = is64 ? ei[2 * (long)e] : ei[e];
        int dst = is64 ? ei[2 * ((long)E + e)] : ei[E + e];
        int slot = atomicAdd(&cursor[dst], 1);
        csr[slot] = src;
    }
}

// ---------------------------------------------------------------------------
// K6: h = X @ W^T, alpha_s = h @ a_src, alpha_d = h @ a_dst  (fused)
// One wave per GROUP of 8 nodes; lane j computes h[n][j] for all 8 nodes.
// 8 independent accumulator chains break the dependent-FMA latency chain;
// one padded W-b128 LDS read amortizes over 8 nodes (LDS << capacity).
// X rows are read once via broadcast (uniform-address) float4 global loads.
// ---------------------------------------------------------------------------
template <int IN_DIM>
__global__ __launch_bounds__(256) void gemm_alpha_kernel(
    const float* __restrict__ X, const float* __restrict__ W,
    const float* __restrict__ a_src, const float* __restrict__ a_dst,
    float* __restrict__ H, float* __restrict__ AS, float* __restrict__ AD, int n) {
    constexpr int LDW = IN_DIM + 4;  // pad: ds_read_b128 start bank = (4j+k)%32, perfect rotation
    __shared__ float sW[64 * LDW];
    int t = threadIdx.x;
    for (int idx = t; idx < 64 * IN_DIM; idx += 256) {
        int r = idx / IN_DIM, c = idx - r * IN_DIM;
        sW[r * LDW + c] = W[idx];
    }
    __syncthreads();
    int lane = t & 63, wid = t >> 6;
    float asj = a_src[lane], adj = a_dst[lane];
    const float* wrow = &sW[lane * LDW];
    int gw = blockIdx.x * 4 + wid;   // global wave id
    int nw = gridDim.x * 4;
    int ngroups = (n + 7) >> 3;
    for (int g = gw; g < ngroups; g += nw) {
        int n0 = g << 3;
        if (n0 + 8 <= n) {
            const float* xr = X + (size_t)n0 * IN_DIM;
            float acc[8];
#pragma unroll
            for (int u = 0; u < 8; ++u) acc[u] = 0.f;
#pragma unroll 4
            for (int k = 0; k < IN_DIM; k += 4) {
                float4 wv = *reinterpret_cast<const float4*>(wrow + k);
#pragma unroll
                for (int u = 0; u < 8; ++u) {
                    float4 xv = *reinterpret_cast<const float4*>(xr + u * IN_DIM + k);
                    acc[u] += xv.x * wv.x + xv.y * wv.y + xv.z * wv.z + xv.w * wv.w;
                }
            }
#pragma unroll
            for (int u = 0; u < 8; ++u) {
                H[(size_t)(n0 + u) * 64 + lane] = acc[u];
                float c1 = acc[u] * asj, c2 = acc[u] * adj;
#pragma unroll
                for (int d = 32; d >= 1; d >>= 1) {
                    c1 += __shfl_xor(c1, d, 64);
                    c2 += __shfl_xor(c2, d, 64);
                }
                if (lane == 0) {
                    AS[n0 + u] = c1;
                    AD[n0 + u] = c2;
                }
            }
        } else {
            // tail group (not hit for n % 8 == 0, kept for generality)
            for (int i = n0; i < n; ++i) {
                const float* xr = X + (size_t)i * IN_DIM;
                float acc = 0.f;
#pragma unroll 4
                for (int k = 0; k < IN_DIM; k += 4) {
                    float4 xv = *reinterpret_cast<const float4*>(xr + k);
                    float4 wv = *reinterpret_cast<const float4*>(wrow + k);
                    acc += xv.x * wv.x + xv.y * wv.y + xv.z * wv.z + xv.w * wv.w;
                }
                H[(size_t)i * 64 + lane] = acc;
                float c1 = acc * asj, c2 = acc * adj;
#pragma unroll
                for (int d = 32; d >= 1; d >>= 1) {
                    c1 += __shfl_xor(c1, d, 64);
                    c2 += __shfl_xor(c2, d, 64);
                }
                if (lane == 0) {
                    AS[i] = c1;
                    AD[i] = c2;
                }
            }
        }
    }
}

// ---------------------------------------------------------------------------
// K7: per-destination-node softmax + aggregation. One wave per node.
// ---------------------------------------------------------------------------
template <bool RELU>
__global__ __launch_bounds__(256) void aggregate_kernel(
    const float* __restrict__ AS, const float* __restrict__ AD,
    const float* __restrict__ H, const int* __restrict__ off,
    const int* __restrict__ csr, const float* __restrict__ bias,
    float* __restrict__ out, int n) {
    int lane = threadIdx.x & 63, wid = threadIdx.x >> 6;
    int i = blockIdx.x * 4 + wid;
    if (i >= n) return;
    int s = off[i], e = off[i + 1];
    float ad = AD[i];

    // Pass A: online max / sum
    float m = -1e30f, ssum = 0.f;
    for (int k = s + lane; k < e; k += 64) {
        int sc = csr[k];
        float ev = AS[sc] + ad;
        ev = ev > 0.f ? ev : NEG_SLOPE * ev;
        float nm = fmaxf(m, ev);
        ssum = ssum * __expf(m - nm) + __expf(ev - nm);
        m = nm;
    }
#pragma unroll
    for (int d = 32; d >= 1; d >>= 1) {
        float om = __shfl_xor(m, d, 64);
        float os = __shfl_xor(ssum, d, 64);
        float nm = fmaxf(m, om);
        ssum = ssum * __expf(m - nm) + os * __expf(om - nm);
        m = nm;
    }
    float inv = 1.0f / ssum;

    // Pass B: aggregate; chunk edges 64 at a time, redistribute via shfl
    float acc = 0.f;
    for (int kb = s; kb < e; kb += 64) {
        int k = kb + lane;
        float ev = -1e30f;
        int sc = 0;
        if (k < e) {
            sc = csr[k];
            ev = AS[sc] + ad;
            ev = ev > 0.f ? ev : NEG_SLOPE * ev;
        }
        float p = __expf(ev - m) * inv;  // 0 for OOB lanes
        int cnt = min(64, e - kb);
        for (int u = 0; u < cnt; ++u) {
            float coef = __shfl(p, u, 64);
            int scu = __shfl(sc, u, 64);
            acc += coef * H[(size_t)scu * 64 + lane];  // coalesced 256B row
        }
    }
    acc += bias[lane];
    if (RELU) acc = fmaxf(acc, 0.f);
    out[(size_t)i * 64 + lane] = acc;
}

// ---------------------------------------------------------------------------
extern "C" void kernel_launch(void* const* d_in, const int* in_sizes, int n_in,
                              void* d_out, int out_size, void* d_ws, size_t ws_size,
                              hipStream_t stream) {
    const float* x   = (const float*)d_in[0];
    const int*   ei  = (const int*)d_in[1];
    const float* W1  = (const float*)d_in[2];
    const float* a1s = (const float*)d_in[3];
    const float* a1d = (const float*)d_in[4];
    const float* b1  = (const float*)d_in[5];
    const float* W2  = (const float*)d_in[6];
    const float* a2s = (const float*)d_in[7];
    const float* a2d = (const float*)d_in[8];
    const float* b2  = (const float*)d_in[9];
    float* out = (float*)d_out;

    int n = in_sizes[0] / 128;
    int E = in_sizes[1] / 2;
    int ET = E + n;

    char* ws = (char*)d_ws;
    size_t o = 0;
    auto alloc = [&](size_t bytes) {
        void* p = ws + o;
        o += (bytes + 255) & ~(size_t)255;
        return p;
    };
    int*   flag   = (int*)alloc(4);
    int*   deg    = (int*)alloc((size_t)n * 4);
    int*   off    = (int*)alloc(((size_t)n + 1) * 4);
    int*   cursor = (int*)alloc((size_t)n * 4);
    int*   csr    = (int*)alloc((size_t)ET * 4);
    float* h1     = (float*)alloc((size_t)n * 64 * 4);
    float* as1    = (float*)alloc((size_t)n * 4);
    float* ad1    = (float*)alloc((size_t)n * 4);
    float* hr1    = (float*)alloc((size_t)n * 64 * 4);
    float* as2    = (float*)alloc((size_t)n * 4);
    float* ad2    = (float*)alloc((size_t)n * 4);
    (void)ws_size; (void)n_in; (void)out_size;

    int nb256 = (n + 255) / 256;
    // 8 nodes per wave-group; 4 waves/block; 2 groups per wave -> balanced grid
    int ngroups = (n + 7) / 8;
    int gemm_blocks = (ngroups + 7) / 8;

    detect_kernel<<<1, 64, 0, stream>>>(ei, flag);
    init_deg_kernel<<<nb256, 256, 0, stream>>>(deg, n);
    count_kernel<<<2048, 256, 0, stream>>>(ei, E, deg, flag);
    scan_kernel<<<1, 1024, 0, stream>>>(deg, off, n);
    selfloop_kernel<<<nb256, 256, 0, stream>>>(off, cursor, csr, n);
    fill_kernel<<<2048, 256, 0, stream>>>(ei, E, cursor, csr, flag);

    // Layer 1
    gemm_alpha_kernel<128><<<gemm_blocks, 256, 0, stream>>>(x, W1, a1s, a1d, h1, as1, ad1, n);
    aggregate_kernel<true><<<(n + 3) / 4, 256, 0, stream>>>(as1, ad1, h1, off, csr, b1, hr1, n);

    // Layer 2 (reuse h1 as h2)
    gemm_alpha_kernel<64><<<gemm_blocks, 256, 0, stream>>>(hr1, W2, a2s, a2d, h1, as2, ad2, n);
    aggregate_kernel<false><<<(n + 3) / 4, 256, 0, stream>>>(as2, ad2, h1, off, csr, b2, out, n);
}

// Round 9
// 399.731 us; speedup vs baseline: 1.1852x; 1.1852x over previous
//
#include <hip/hip_runtime.h>
#include <cstdint>
#include <cstddef>

#ifndef NEG_SLOPE
#define NEG_SLOPE 0.2f
#endif

typedef __attribute__((ext_vector_type(8))) short short8;
typedef __attribute__((ext_vector_type(4))) float f32x4;

__device__ __forceinline__ unsigned short bf16rne(float f) {
    unsigned u = __builtin_bit_cast(unsigned, f);
    u += 0x7FFFu + ((u >> 16) & 1u);
    return (unsigned short)(u >> 16);
}
__device__ __forceinline__ float bf16tof(unsigned short h) {
    unsigned u = ((unsigned)h) << 16;
    return __builtin_bit_cast(float, u);
}

// ---------------------------------------------------------------------------
// K0: detect whether edge_index is stored as int64 (low/high int32 pairs) or
// int32. Values are node ids in [0, 50000) so int64 high words are all zero.
// ---------------------------------------------------------------------------
__global__ void detect_kernel(const int* __restrict__ ei, int* __restrict__ flag) {
    if (threadIdx.x == 0 && blockIdx.x == 0) {
        int orv = 0;
#pragma unroll
        for (int k = 0; k < 16; ++k) orv |= ei[2 * k + 1];
        *flag = (orv == 0) ? 1 : 0;
    }
}

// K1: deg[i] = 1 (self loop)
__global__ void init_deg_kernel(int* __restrict__ deg, int n) {
    int i = blockIdx.x * blockDim.x + threadIdx.x;
    if (i < n) deg[i] = 1;
}

// K2: count in-degrees
__global__ void count_kernel(const int* __restrict__ ei, int E,
                             int* __restrict__ deg, const int* __restrict__ flag) {
    int is64 = *flag;
    int stride = gridDim.x * blockDim.x;
    for (int e = blockIdx.x * blockDim.x + threadIdx.x; e < E; e += stride) {
        int dst = is64 ? ei[2 * ((long)E + e)] : ei[E + e];
        atomicAdd(&deg[dst], 1);
    }
}

// K3: exclusive scan deg -> off (single block, wave-scan based)
__global__ __launch_bounds__(1024) void scan_kernel(const int* __restrict__ deg,
                                                    int* __restrict__ off, int n) {
    __shared__ int wsum[16];
    __shared__ int carry_s;
    int t = threadIdx.x;
    int lane = t & 63, wid = t >> 6;
    if (t == 0) carry_s = 0;
    __syncthreads();
    for (int base = 0; base < n; base += 1024) {
        int idx = base + t;
        int v = (idx < n) ? deg[idx] : 0;
        int inc = v;
#pragma unroll
        for (int d = 1; d < 64; d <<= 1) {
            int o = __shfl_up(inc, d, 64);
            if (lane >= d) inc += o;
        }
        if (lane == 63) wsum[wid] = inc;
        __syncthreads();
        int carry = carry_s;
        int wpre = 0;
        for (int w = 0; w < wid; ++w) wpre += wsum[w];
        if (idx < n) off[idx] = carry + wpre + inc - v;
        __syncthreads();
        if (t == 1023) carry_s = carry + wpre + inc;
    }
    __syncthreads();
    if (t == 0) off[n] = carry_s;
}

// K4: place self-loop at the head of each node's bucket, init cursor
__global__ void selfloop_kernel(const int* __restrict__ off, int* __restrict__ cursor,
                                int* __restrict__ csr, int n) {
    int i = blockIdx.x * blockDim.x + threadIdx.x;
    if (i < n) {
        int o = off[i];
        csr[o] = i;
        cursor[i] = o + 1;
    }
}

// K5: scatter edges into CSR buckets (store src id)
__global__ void fill_kernel(const int* __restrict__ ei, int E,
                            int* __restrict__ cursor, int* __restrict__ csr,
                            const int* __restrict__ flag) {
    int is64 = *flag;
    int stride = gridDim.x * blockDim.x;
    for (int e = blockIdx.x * blockDim.x + threadIdx.x; e < E; e += stride) {
        int src = is64 ? ei[2 * (long)e] : ei[e];
        int dst = is64 ? ei[2 * ((long)E + e)] : ei[E + e];
        int slot = atomicAdd(&cursor[dst], 1);
        csr[slot] = src;
    }
}

// ---------------------------------------------------------------------------
// K6 (MFMA): H = X @ W^T + fused alpha_s/alpha_d, split-bf16 (hi/lo) for
// fp32-class accuracy: X·W ≈ Xhi·Whi + Xhi·Wlo + Xlo·Whi (lo·lo dropped,
// ~2^-18 relative). One wave per 16 nodes; 4 N-tiles of 16 cols each via
// v_mfma_f32_16x16x32_bf16. A-fragments built in registers from coalesced
// global loads (lane l: 32B of row n0+(l&15) at k-quarter (l>>4) -> 64
// distinct fully-used 64B lines per load instr, deep MLP). W converted to
// bf16 hi/lo in LDS once per block; +8-elem row pad -> balanced banks.
// C/D layout (verified m89/m91): col = lane&15, row = (lane>>4)*4 + reg.
// ---------------------------------------------------------------------------
template <int IN_DIM>
__global__ __launch_bounds__(256) void gemm_mfma_kernel(
    const float* __restrict__ X, const float* __restrict__ W,
    const float* __restrict__ a_src, const float* __restrict__ a_dst,
    float* __restrict__ H, float* __restrict__ AS, float* __restrict__ AD, int n) {
    constexpr int KT  = IN_DIM / 32;   // k-tiles of 32
    constexpr int LDB = IN_DIM + 8;    // padded W row (bf16 elems); row bytes mult of 16
    __shared__ unsigned short sWhi[64 * LDB];
    __shared__ unsigned short sWlo[64 * LDB];
    int t = threadIdx.x;
    for (int idx = t; idx < 64 * IN_DIM; idx += 256) {
        int r = idx / IN_DIM, c = idx - r * IN_DIM;
        float w = W[idx];
        unsigned short hi = bf16rne(w);
        sWhi[r * LDB + c] = hi;
        sWlo[r * LDB + c] = bf16rne(w - bf16tof(hi));
    }
    __syncthreads();
    int lane = t & 63, wid = t >> 6;
    int l15 = lane & 15, l4 = lane >> 4;
    float asj[4], adj[4];
#pragma unroll
    for (int nt = 0; nt < 4; ++nt) {
        asj[nt] = a_src[nt * 16 + l15];
        adj[nt] = a_dst[nt * 16 + l15];
    }
    int gw = blockIdx.x * 4 + wid;
    int nw = gridDim.x * 4;
    int mtiles = n >> 4;  // n % 16 == 0 for this problem (50000)
    for (int tile = gw; tile < mtiles; tile += nw) {
        int n0 = tile << 4;
        f32x4 acc[4];
#pragma unroll
        for (int nt = 0; nt < 4; ++nt) acc[nt] = f32x4{0.f, 0.f, 0.f, 0.f};
        const float* xbase = X + (size_t)(n0 + l15) * IN_DIM + l4 * 8;
#pragma unroll
        for (int kt = 0; kt < KT; ++kt) {
            float4 v0 = *reinterpret_cast<const float4*>(xbase + kt * 32);
            float4 v1 = *reinterpret_cast<const float4*>(xbase + kt * 32 + 4);
            float xv[8] = {v0.x, v0.y, v0.z, v0.w, v1.x, v1.y, v1.z, v1.w};
            short8 ahi, alo;
#pragma unroll
            for (int e = 0; e < 8; ++e) {
                unsigned short hb = bf16rne(xv[e]);
                ahi[e] = (short)hb;
                alo[e] = (short)bf16rne(xv[e] - bf16tof(hb));
            }
            int kcol = kt * 32 + l4 * 8;
#pragma unroll
            for (int nt = 0; nt < 4; ++nt) {
                short8 bhi = *reinterpret_cast<const short8*>(&sWhi[(nt * 16 + l15) * LDB + kcol]);
                short8 blo = *reinterpret_cast<const short8*>(&sWlo[(nt * 16 + l15) * LDB + kcol]);
                acc[nt] = __builtin_amdgcn_mfma_f32_16x16x32_bf16(ahi, bhi, acc[nt], 0, 0, 0);
                acc[nt] = __builtin_amdgcn_mfma_f32_16x16x32_bf16(ahi, blo, acc[nt], 0, 0, 0);
                acc[nt] = __builtin_amdgcn_mfma_f32_16x16x32_bf16(alo, bhi, acc[nt], 0, 0, 0);
            }
        }
        // epilogue: H store + alpha reductions (rows = l4*4 + r, cols = nt*16 + l15)
        float c1[4] = {0.f, 0.f, 0.f, 0.f}, c2[4] = {0.f, 0.f, 0.f, 0.f};
#pragma unroll
        for (int nt = 0; nt < 4; ++nt) {
#pragma unroll
            for (int r = 0; r < 4; ++r) {
                float h = acc[nt][r];
                H[(size_t)(n0 + l4 * 4 + r) * 64 + nt * 16 + l15] = h;
                c1[r] += h * asj[nt];
                c2[r] += h * adj[nt];
            }
        }
#pragma unroll
        for (int r = 0; r < 4; ++r) {
#pragma unroll
            for (int d = 1; d < 16; d <<= 1) {
                c1[r] += __shfl_xor(c1[r], d, 64);
                c2[r] += __shfl_xor(c2[r], d, 64);
            }
            if (l15 == 0) {
                AS[n0 + l4 * 4 + r] = c1[r];
                AD[n0 + l4 * 4 + r] = c2[r];
            }
        }
    }
}

// ---------------------------------------------------------------------------
// K7: per-destination-node softmax + aggregation. One wave per node.
// ---------------------------------------------------------------------------
template <bool RELU>
__global__ __launch_bounds__(256) void aggregate_kernel(
    const float* __restrict__ AS, const float* __restrict__ AD,
    const float* __restrict__ H, const int* __restrict__ off,
    const int* __restrict__ csr, const float* __restrict__ bias,
    float* __restrict__ out, int n) {
    int lane = threadIdx.x & 63, wid = threadIdx.x >> 6;
    int i = blockIdx.x * 4 + wid;
    if (i >= n) return;
    int s = off[i], e = off[i + 1];
    float ad = AD[i];

    // Pass A: online max / sum
    float m = -1e30f, ssum = 0.f;
    for (int k = s + lane; k < e; k += 64) {
        int sc = csr[k];
        float ev = AS[sc] + ad;
        ev = ev > 0.f ? ev : NEG_SLOPE * ev;
        float nm = fmaxf(m, ev);
        ssum = ssum * __expf(m - nm) + __expf(ev - nm);
        m = nm;
    }
#pragma unroll
    for (int d = 32; d >= 1; d >>= 1) {
        float om = __shfl_xor(m, d, 64);
        float os = __shfl_xor(ssum, d, 64);
        float nm = fmaxf(m, om);
        ssum = ssum * __expf(m - nm) + os * __expf(om - nm);
        m = nm;
    }
    float inv = 1.0f / ssum;

    // Pass B: aggregate; chunk edges 64 at a time, redistribute via shfl
    float acc = 0.f;
    for (int kb = s; kb < e; kb += 64) {
        int k = kb + lane;
        float ev = -1e30f;
        int sc = 0;
        if (k < e) {
            sc = csr[k];
            ev = AS[sc] + ad;
            ev = ev > 0.f ? ev : NEG_SLOPE * ev;
        }
        float p = __expf(ev - m) * inv;  // 0 for OOB lanes
        int cnt = min(64, e - kb);
        for (int u = 0; u < cnt; ++u) {
            float coef = __shfl(p, u, 64);
            int scu = __shfl(sc, u, 64);
            acc += coef * H[(size_t)scu * 64 + lane];  // coalesced 256B row
        }
    }
    acc += bias[lane];
    if (RELU) acc = fmaxf(acc, 0.f);
    out[(size_t)i * 64 + lane] = acc;
}

// ---------------------------------------------------------------------------
extern "C" void kernel_launch(void* const* d_in, const int* in_sizes, int n_in,
                              void* d_out, int out_size, void* d_ws, size_t ws_size,
                              hipStream_t stream) {
    const float* x   = (const float*)d_in[0];
    const int*   ei  = (const int*)d_in[1];
    const float* W1  = (const float*)d_in[2];
    const float* a1s = (const float*)d_in[3];
    const float* a1d = (const float*)d_in[4];
    const float* b1  = (const float*)d_in[5];
    const float* W2  = (const float*)d_in[6];
    const float* a2s = (const float*)d_in[7];
    const float* a2d = (const float*)d_in[8];
    const float* b2  = (const float*)d_in[9];
    float* out = (float*)d_out;

    int n = in_sizes[0] / 128;
    int E = in_sizes[1] / 2;
    int ET = E + n;

    char* ws = (char*)d_ws;
    size_t o = 0;
    auto alloc = [&](size_t bytes) {
        void* p = ws + o;
        o += (bytes + 255) & ~(size_t)255;
        return p;
    };
    int*   flag   = (int*)alloc(4);
    int*   deg    = (int*)alloc((size_t)n * 4);
    int*   off    = (int*)alloc(((size_t)n + 1) * 4);
    int*   cursor = (int*)alloc((size_t)n * 4);
    int*   csr    = (int*)alloc((size_t)ET * 4);
    float* h1     = (float*)alloc((size_t)n * 64 * 4);
    float* as1    = (float*)alloc((size_t)n * 4);
    float* ad1    = (float*)alloc((size_t)n * 4);
    float* hr1    = (float*)alloc((size_t)n * 64 * 4);
    float* as2    = (float*)alloc((size_t)n * 4);
    float* ad2    = (float*)alloc((size_t)n * 4);
    (void)ws_size; (void)n_in; (void)out_size;

    int nb256 = (n + 255) / 256;
    int mtiles = n / 16;                      // 3125 for n=50000
    int gemm_blocks = (mtiles + 3) / 4;       // 1 tile per wave

    detect_kernel<<<1, 64, 0, stream>>>(ei, flag);
    init_deg_kernel<<<nb256, 256, 0, stream>>>(deg, n);
    count_kernel<<<2048, 256, 0, stream>>>(ei, E, deg, flag);
    scan_kernel<<<1, 1024, 0, stream>>>(deg, off, n);
    selfloop_kernel<<<nb256, 256, 0, stream>>>(off, cursor, csr, n);
    fill_kernel<<<2048, 256, 0, stream>>>(ei, E, cursor, csr, flag);

    // Layer 1
    gemm_mfma_kernel<128><<<gemm_blocks, 256, 0, stream>>>(x, W1, a1s, a1d, h1, as1, ad1, n);
    aggregate_kernel<true><<<(n + 3) / 4, 256, 0, stream>>>(as1, ad1, h1, off, csr, b1, hr1, n);

    // Layer 2 (reuse h1 as h2)
    gemm_mfma_kernel<64><<<gemm_blocks, 256, 0, stream>>>(hr1, W2, a2s, a2d, h1, as2, ad2, n);
    aggregate_kernel<false><<<(n + 3) / 4, 256, 0, stream>>>(as2, ad2, h1, off, csr, b2, out, n);
}

// Round 11
// 299.219 us; speedup vs baseline: 1.5833x; 1.3359x over previous
//
#include <hip/hip_runtime.h>
#include <cstdint>
#include <cstddef>

#ifndef NEG_SLOPE
#define NEG_SLOPE 0.2f
#endif

typedef __attribute__((ext_vector_type(8))) short short8;
typedef __attribute__((ext_vector_type(4))) float f32x4;

__device__ __forceinline__ unsigned short bf16rne(float f) {
    unsigned u = __builtin_bit_cast(unsigned, f);
    u += 0x7FFFu + ((u >> 16) & 1u);
    return (unsigned short)(u >> 16);
}
__device__ __forceinline__ float bf16tof(unsigned short h) {
    unsigned u = ((unsigned)h) << 16;
    return __builtin_bit_cast(float, u);
}

// ---------------------------------------------------------------------------
// K0: detect int64 vs int32 storage of edge_index (node ids < 50000 -> int64
// high words all zero).
// ---------------------------------------------------------------------------
__global__ void detect_kernel(const int* __restrict__ ei, int* __restrict__ flag) {
    if (threadIdx.x == 0 && blockIdx.x == 0) {
        int orv = 0;
#pragma unroll
        for (int k = 0; k < 16; ++k) orv |= ei[2 * k + 1];
        *flag = (orv == 0) ? 1 : 0;
    }
}

// K1: deg[i] = 1 (self loop)
__global__ void init_deg_kernel(int* __restrict__ deg, int n) {
    int i = blockIdx.x * blockDim.x + threadIdx.x;
    if (i < n) deg[i] = 1;
}

// K2: count in-degrees
__global__ void count_kernel(const int* __restrict__ ei, int E,
                             int* __restrict__ deg, const int* __restrict__ flag) {
    int is64 = *flag;
    int stride = gridDim.x * blockDim.x;
    for (int e = blockIdx.x * blockDim.x + threadIdx.x; e < E; e += stride) {
        int dst = is64 ? ei[2 * ((long)E + e)] : ei[E + e];
        atomicAdd(&deg[dst], 1);
    }
}

// ---------------------------------------------------------------------------
// K3a/b/c: multi-block exclusive scan.
// ---------------------------------------------------------------------------
__global__ __launch_bounds__(256) void scan1_kernel(const int* __restrict__ deg,
                                                    int* __restrict__ off,
                                                    int* __restrict__ bsum, int n) {
    __shared__ int ws[4];
    int t = threadIdx.x, lane = t & 63, w = t >> 6;
    int idx = blockIdx.x * 256 + t;
    int v = (idx < n) ? deg[idx] : 0;
    int inc = v;
#pragma unroll
    for (int d = 1; d < 64; d <<= 1) {
        int o = __shfl_up(inc, d, 64);
        if (lane >= d) inc += o;
    }
    if (lane == 63) ws[w] = inc;
    __syncthreads();
    int wpre = 0;
    for (int x = 0; x < w; ++x) wpre += ws[x];
    if (idx < n) off[idx] = wpre + inc - v;
    if (t == 255) bsum[blockIdx.x] = wpre + inc;
}

__global__ __launch_bounds__(256) void scan2_kernel(int* __restrict__ bsum,
                                                    int* __restrict__ total, int nb) {
    __shared__ int ws[4];
    int t = threadIdx.x, lane = t & 63, w = t >> 6;
    int v = (t < nb) ? bsum[t] : 0;
    int inc = v;
#pragma unroll
    for (int d = 1; d < 64; d <<= 1) {
        int o = __shfl_up(inc, d, 64);
        if (lane >= d) inc += o;
    }
    if (lane == 63) ws[w] = inc;
    __syncthreads();
    int wpre = 0;
    for (int x = 0; x < w; ++x) wpre += ws[x];
    if (t < nb) bsum[t] = wpre + inc - v;   // own-slot write, no cross-slot hazard
    if (t == 255) *total = wpre + inc;
}

__global__ __launch_bounds__(256) void scan3_kernel(int* __restrict__ off,
                                                    const int* __restrict__ bsum,
                                                    const int* __restrict__ total, int n) {
    int idx = blockIdx.x * 256 + threadIdx.x;
    if (idx < n) off[idx] += bsum[blockIdx.x];
    if (idx == 0) off[n] = *total;
}

// K4: place self-loop at the head of each node's bucket, init cursor
__global__ void selfloop_kernel(const int* __restrict__ off, int* __restrict__ cursor,
                                int* __restrict__ csr, int n) {
    int i = blockIdx.x * blockDim.x + threadIdx.x;
    if (i < n) {
        int o = off[i];
        csr[o] = i;
        cursor[i] = o + 1;
    }
}

// K5: scatter edges into CSR buckets (store src id)
__global__ void fill_kernel(const int* __restrict__ ei, int E,
                            int* __restrict__ cursor, int* __restrict__ csr,
                            const int* __restrict__ flag) {
    int is64 = *flag;
    int stride = gridDim.x * blockDim.x;
    for (int e = blockIdx.x * blockDim.x + threadIdx.x; e < E; e += stride) {
        int src = is64 ? ei[2 * (long)e] : ei[e];
        int dst = is64 ? ei[2 * ((long)E + e)] : ei[E + e];
        int slot = atomicAdd(&cursor[dst], 1);
        csr[slot] = src;
    }
}

// ---------------------------------------------------------------------------
// K6 (MFMA): H = X @ W^T + fused alpha_s/alpha_d, split-bf16 (hi/lo).
// (unchanged — measured good in round 9)
// ---------------------------------------------------------------------------
template <int IN_DIM>
__global__ __launch_bounds__(256) void gemm_mfma_kernel(
    const float* __restrict__ X, const float* __restrict__ W,
    const float* __restrict__ a_src, const float* __restrict__ a_dst,
    float* __restrict__ H, float* __restrict__ AS, float* __restrict__ AD, int n) {
    constexpr int KT  = IN_DIM / 32;
    constexpr int LDB = IN_DIM + 8;
    __shared__ unsigned short sWhi[64 * LDB];
    __shared__ unsigned short sWlo[64 * LDB];
    int t = threadIdx.x;
    for (int idx = t; idx < 64 * IN_DIM; idx += 256) {
        int r = idx / IN_DIM, c = idx - r * IN_DIM;
        float w = W[idx];
        unsigned short hi = bf16rne(w);
        sWhi[r * LDB + c] = hi;
        sWlo[r * LDB + c] = bf16rne(w - bf16tof(hi));
    }
    __syncthreads();
    int lane = t & 63, wid = t >> 6;
    int l15 = lane & 15, l4 = lane >> 4;
    float asj[4], adj[4];
#pragma unroll
    for (int nt = 0; nt < 4; ++nt) {
        asj[nt] = a_src[nt * 16 + l15];
        adj[nt] = a_dst[nt * 16 + l15];
    }
    int gw = blockIdx.x * 4 + wid;
    int nw = gridDim.x * 4;
    int mtiles = n >> 4;
    for (int tile = gw; tile < mtiles; tile += nw) {
        int n0 = tile << 4;
        f32x4 acc[4];
#pragma unroll
        for (int nt = 0; nt < 4; ++nt) acc[nt] = f32x4{0.f, 0.f, 0.f, 0.f};
        const float* xbase = X + (size_t)(n0 + l15) * IN_DIM + l4 * 8;
#pragma unroll
        for (int kt = 0; kt < KT; ++kt) {
            float4 v0 = *reinterpret_cast<const float4*>(xbase + kt * 32);
            float4 v1 = *reinterpret_cast<const float4*>(xbase + kt * 32 + 4);
            float xv[8] = {v0.x, v0.y, v0.z, v0.w, v1.x, v1.y, v1.z, v1.w};
            short8 ahi, alo;
#pragma unroll
            for (int e = 0; e < 8; ++e) {
                unsigned short hb = bf16rne(xv[e]);
                ahi[e] = (short)hb;
                alo[e] = (short)bf16rne(xv[e] - bf16tof(hb));
            }
            int kcol = kt * 32 + l4 * 8;
#pragma unroll
            for (int nt = 0; nt < 4; ++nt) {
                short8 bhi = *reinterpret_cast<const short8*>(&sWhi[(nt * 16 + l15) * LDB + kcol]);
                short8 blo = *reinterpret_cast<const short8*>(&sWlo[(nt * 16 + l15) * LDB + kcol]);
                acc[nt] = __builtin_amdgcn_mfma_f32_16x16x32_bf16(ahi, bhi, acc[nt], 0, 0, 0);
                acc[nt] = __builtin_amdgcn_mfma_f32_16x16x32_bf16(ahi, blo, acc[nt], 0, 0, 0);
                acc[nt] = __builtin_amdgcn_mfma_f32_16x16x32_bf16(alo, bhi, acc[nt], 0, 0, 0);
            }
        }
        float c1[4] = {0.f, 0.f, 0.f, 0.f}, c2[4] = {0.f, 0.f, 0.f, 0.f};
#pragma unroll
        for (int nt = 0; nt < 4; ++nt) {
#pragma unroll
            for (int r = 0; r < 4; ++r) {
                float h = acc[nt][r];
                H[(size_t)(n0 + l4 * 4 + r) * 64 + nt * 16 + l15] = h;
                c1[r] += h * asj[nt];
                c2[r] += h * adj[nt];
            }
        }
#pragma unroll
        for (int r = 0; r < 4; ++r) {
#pragma unroll
            for (int d = 1; d < 16; d <<= 1) {
                c1[r] += __shfl_xor(c1[r], d, 64);
                c2[r] += __shfl_xor(c2[r], d, 64);
            }
            if (l15 == 0) {
                AS[n0 + l4 * 4 + r] = c1[r];
                AD[n0 + l4 * 4 + r] = c2[r];
            }
        }
    }
}

// ---------------------------------------------------------------------------
// K7: per-dst softmax + aggregation, one wave per node.
// Pass A: lanes parallel over edges: compute ev, stash (ev, src) in LDS
// (CAP=128), online max/sum + wave reduce.
// Pass B: shfl-FREE serial loop over LDS-staged edges; lane owns dim `lane`;
// 4-way unrolled independent H-row gathers for MLP; inv deferred to epilogue.
// deg>CAP fallback recomputes via uniform loads (never hit at Poisson(17)).
// ---------------------------------------------------------------------------
template <bool RELU>
__global__ __launch_bounds__(256) void aggregate_kernel(
    const float* __restrict__ AS, const float* __restrict__ AD,
    const float* __restrict__ H, const int* __restrict__ off,
    const int* __restrict__ csr, const float* __restrict__ bias,
    float* __restrict__ out, int n) {
    constexpr int CAP = 128;
    __shared__ float2 sEdge[4][CAP];
    int lane = threadIdx.x & 63, wid = threadIdx.x >> 6;
    int i = blockIdx.x * 4 + wid;
    if (i >= n) return;
    int s = off[i], e = off[i + 1];
    int deg = e - s;
    float ad = AD[i];
    float2* st = sEdge[wid];

    // Pass A
    float m = -1e30f, ssum = 0.f;
    for (int k = s + lane; k < e; k += 64) {
        int sc = csr[k];
        float ev = AS[sc] + ad;
        ev = ev > 0.f ? ev : NEG_SLOPE * ev;
        int idx = k - s;
        if (idx < CAP) st[idx] = make_float2(ev, __int_as_float(sc));
        float nm = fmaxf(m, ev);
        ssum = ssum * __expf(m - nm) + __expf(ev - nm);
        m = nm;
    }
#pragma unroll
    for (int d = 32; d >= 1; d >>= 1) {
        float om = __shfl_xor(m, d, 64);
        float os = __shfl_xor(ssum, d, 64);
        float nm = fmaxf(m, om);
        ssum = ssum * __expf(m - nm) + os * __expf(om - nm);
        m = nm;
    }
    float inv = 1.0f / ssum;

    // drain this wave's ds_writes before cross-lane LDS reads (no barrier:
    // waves independent; lgkm ops may complete out of order)
    asm volatile("s_waitcnt lgkmcnt(0)" ::: "memory");
    __builtin_amdgcn_sched_barrier(0);

    // Pass B
    float acc = 0.f;
    int lim = deg < CAP ? deg : CAP;
    int k2 = 0;
    for (; k2 + 4 <= lim; k2 += 4) {
        float2 e0 = st[k2 + 0];
        float2 e1 = st[k2 + 1];
        float2 e2 = st[k2 + 2];
        float2 e3 = st[k2 + 3];
        float v0 = H[(size_t)__float_as_int(e0.y) * 64 + lane];
        float v1 = H[(size_t)__float_as_int(e1.y) * 64 + lane];
        float v2 = H[(size_t)__float_as_int(e2.y) * 64 + lane];
        float v3 = H[(size_t)__float_as_int(e3.y) * 64 + lane];
        acc += __expf(e0.x - m) * v0;
        acc += __expf(e1.x - m) * v1;
        acc += __expf(e2.x - m) * v2;
        acc += __expf(e3.x - m) * v3;
    }
    for (; k2 < lim; ++k2) {
        float2 e0 = st[k2];
        acc += __expf(e0.x - m) * H[(size_t)__float_as_int(e0.y) * 64 + lane];
    }
    for (int k = s + CAP; k < e; ++k) {   // deg > CAP fallback (uniform)
        int sc = csr[k];
        float ev = AS[sc] + ad;
        ev = ev > 0.f ? ev : NEG_SLOPE * ev;
        acc += __expf(ev - m) * H[(size_t)sc * 64 + lane];
    }
    acc = acc * inv + bias[lane];
    if (RELU) acc = fmaxf(acc, 0.f);
    out[(size_t)i * 64 + lane] = acc;
}

// ---------------------------------------------------------------------------
extern "C" void kernel_launch(void* const* d_in, const int* in_sizes, int n_in,
                              void* d_out, int out_size, void* d_ws, size_t ws_size,
                              hipStream_t stream) {
    const float* x   = (const float*)d_in[0];
    const int*   ei  = (const int*)d_in[1];
    const float* W1  = (const float*)d_in[2];
    const float* a1s = (const float*)d_in[3];
    const float* a1d = (const float*)d_in[4];
    const float* b1  = (const float*)d_in[5];
    const float* W2  = (const float*)d_in[6];
    const float* a2s = (const float*)d_in[7];
    const float* a2d = (const float*)d_in[8];
    const float* b2  = (const float*)d_in[9];
    float* out = (float*)d_out;

    int n = in_sizes[0] / 128;
    int E = in_sizes[1] / 2;
    int ET = E + n;

    char* ws = (char*)d_ws;
    size_t o = 0;
    auto alloc = [&](size_t bytes) {
        void* p = ws + o;
        o += (bytes + 255) & ~(size_t)255;
        return p;
    };
    int*   flag   = (int*)alloc(4);
    int*   deg    = (int*)alloc((size_t)n * 4);
    int*   off    = (int*)alloc(((size_t)n + 1) * 4);
    int*   cursor = (int*)alloc((size_t)n * 4);
    int*   csr    = (int*)alloc((size_t)ET * 4);
    int*   bsum   = (int*)alloc(256 * 4);
    int*   total  = (int*)alloc(4);
    float* h1     = (float*)alloc((size_t)n * 64 * 4);
    float* as1    = (float*)alloc((size_t)n * 4);
    float* ad1    = (float*)alloc((size_t)n * 4);
    float* hr1    = (float*)alloc((size_t)n * 64 * 4);
    float* as2    = (float*)alloc((size_t)n * 4);
    float* ad2    = (float*)alloc((size_t)n * 4);
    (void)ws_size; (void)n_in; (void)out_size;

    int nb256 = (n + 255) / 256;                // 196 scan blocks (<=256 required)
    int mtiles = n / 16;
    int gemm_blocks = (mtiles + 3) / 4;

    detect_kernel<<<1, 64, 0, stream>>>(ei, flag);
    init_deg_kernel<<<nb256, 256, 0, stream>>>(deg, n);
    count_kernel<<<2048, 256, 0, stream>>>(ei, E, deg, flag);
    scan1_kernel<<<nb256, 256, 0, stream>>>(deg, off, bsum, n);
    scan2_kernel<<<1, 256, 0, stream>>>(bsum, total, nb256);
    scan3_kernel<<<nb256, 256, 0, stream>>>(off, bsum, total, n);
    selfloop_kernel<<<nb256, 256, 0, stream>>>(off, cursor, csr, n);
    fill_kernel<<<2048, 256, 0, stream>>>(ei, E, cursor, csr, flag);

    // Layer 1
    gemm_mfma_kernel<128><<<gemm_blocks, 256, 0, stream>>>(x, W1, a1s, a1d, h1, as1, ad1, n);
    aggregate_kernel<true><<<(n + 3) / 4, 256, 0, stream>>>(as1, ad1, h1, off, csr, b1, hr1, n);

    // Layer 2 (reuse h1 as h2)
    gemm_mfma_kernel<64><<<gemm_blocks, 256, 0, stream>>>(hr1, W2, a2s, a2d, h1, as2, ad2, n);
    aggregate_kernel<false><<<(n + 3) / 4, 256, 0, stream>>>(as2, ad2, h1, off, csr, b2, out, n);
}

// Round 12
// 274.051 us; speedup vs baseline: 1.7287x; 1.0918x over previous
//
#include <hip/hip_runtime.h>
#include <cstdint>
#include <cstddef>

#ifndef NEG_SLOPE
#define NEG_SLOPE 0.2f
#endif

typedef __attribute__((ext_vector_type(8))) short short8;
typedef __attribute__((ext_vector_type(4))) float f32x4;

__device__ __forceinline__ unsigned short bf16rne(float f) {
    unsigned u = __builtin_bit_cast(unsigned, f);
    u += 0x7FFFu + ((u >> 16) & 1u);
    return (unsigned short)(u >> 16);
}
__device__ __forceinline__ float bf16tof(unsigned short h) {
    unsigned u = ((unsigned)h) << 16;
    return __builtin_bit_cast(float, u);
}

// ---------------------------------------------------------------------------
// K0: detect int64 vs int32 storage of edge_index.
// ---------------------------------------------------------------------------
__global__ void detect_kernel(const int* __restrict__ ei, int* __restrict__ flag) {
    if (threadIdx.x == 0 && blockIdx.x == 0) {
        int orv = 0;
#pragma unroll
        for (int k = 0; k < 16; ++k) orv |= ei[2 * k + 1];
        *flag = (orv == 0) ? 1 : 0;
    }
}

// K1: deg[i] = 1 (self loop)
__global__ void init_deg_kernel(int* __restrict__ deg, int n) {
    int i = blockIdx.x * blockDim.x + threadIdx.x;
    if (i < n) deg[i] = 1;
}

// ---------------------------------------------------------------------------
// K2: count in-degrees, dst-partitioned by blockIdx%8 (XCD round-robin):
// partition p's deg lines are touched by one XCD's L2 only -> writes merge.
// Each group re-reads the dst stream (L3-served). Correct for any mapping.
// ---------------------------------------------------------------------------
__global__ void count_kernel(const int* __restrict__ ei, int E, int n,
                             int* __restrict__ deg, const int* __restrict__ flag) {
    int is64 = *flag;
    int part = blockIdx.x & 7;
    int rank = blockIdx.x >> 3;
    int nblk = gridDim.x >> 3;
    int step = (n + 7) >> 3;
    int lo = part * step;
    int hi = lo + step < n ? lo + step : n;
    int stride = nblk * blockDim.x;
    for (int e = rank * blockDim.x + threadIdx.x; e < E; e += stride) {
        int dst = is64 ? ei[2 * ((long)E + e)] : ei[E + e];
        if (dst >= lo && dst < hi) atomicAdd(&deg[dst], 1);
    }
}

// ---------------------------------------------------------------------------
// K3a/b/c: multi-block exclusive scan.
// ---------------------------------------------------------------------------
__global__ __launch_bounds__(256) void scan1_kernel(const int* __restrict__ deg,
                                                    int* __restrict__ off,
                                                    int* __restrict__ bsum, int n) {
    __shared__ int ws[4];
    int t = threadIdx.x, lane = t & 63, w = t >> 6;
    int idx = blockIdx.x * 256 + t;
    int v = (idx < n) ? deg[idx] : 0;
    int inc = v;
#pragma unroll
    for (int d = 1; d < 64; d <<= 1) {
        int o = __shfl_up(inc, d, 64);
        if (lane >= d) inc += o;
    }
    if (lane == 63) ws[w] = inc;
    __syncthreads();
    int wpre = 0;
    for (int x = 0; x < w; ++x) wpre += ws[x];
    if (idx < n) off[idx] = wpre + inc - v;
    if (t == 255) bsum[blockIdx.x] = wpre + inc;
}

__global__ __launch_bounds__(256) void scan2_kernel(int* __restrict__ bsum,
                                                    int* __restrict__ total, int nb) {
    __shared__ int ws[4];
    int t = threadIdx.x, lane = t & 63, w = t >> 6;
    int v = (t < nb) ? bsum[t] : 0;
    int inc = v;
#pragma unroll
    for (int d = 1; d < 64; d <<= 1) {
        int o = __shfl_up(inc, d, 64);
        if (lane >= d) inc += o;
    }
    if (lane == 63) ws[w] = inc;
    __syncthreads();
    int wpre = 0;
    for (int x = 0; x < w; ++x) wpre += ws[x];
    if (t < nb) bsum[t] = wpre + inc - v;
    if (t == 255) *total = wpre + inc;
}

__global__ __launch_bounds__(256) void scan3_kernel(int* __restrict__ off,
                                                    const int* __restrict__ bsum,
                                                    const int* __restrict__ total, int n) {
    int idx = blockIdx.x * 256 + threadIdx.x;
    if (idx < n) off[idx] += bsum[blockIdx.x];
    if (idx == 0) off[n] = *total;
}

// K4: self-loop at bucket head, init cursor
__global__ void selfloop_kernel(const int* __restrict__ off, int* __restrict__ cursor,
                                int* __restrict__ csr, int n) {
    int i = blockIdx.x * blockDim.x + threadIdx.x;
    if (i < n) {
        int o = off[i];
        csr[o] = i;
        cursor[i] = o + 1;
    }
}

// ---------------------------------------------------------------------------
// K5: scatter edges into CSR, dst-partitioned like count. Partition p writes
// the CONTIGUOUS csr slice [off[lo], off[hi]) from one XCD -> line merging
// in that XCD's L2, writeback ~= data size instead of 16x amplification.
// ---------------------------------------------------------------------------
__global__ void fill_kernel(const int* __restrict__ ei, int E, int n,
                            int* __restrict__ cursor, int* __restrict__ csr,
                            const int* __restrict__ flag) {
    int is64 = *flag;
    int part = blockIdx.x & 7;
    int rank = blockIdx.x >> 3;
    int nblk = gridDim.x >> 3;
    int step = (n + 7) >> 3;
    int lo = part * step;
    int hi = lo + step < n ? lo + step : n;
    int stride = nblk * blockDim.x;
    for (int e = rank * blockDim.x + threadIdx.x; e < E; e += stride) {
        int dst = is64 ? ei[2 * ((long)E + e)] : ei[E + e];
        if (dst >= lo && dst < hi) {
            int src = is64 ? ei[2 * (long)e] : ei[e];
            int slot = atomicAdd(&cursor[dst], 1);
            csr[slot] = src;
        }
    }
}

// ---------------------------------------------------------------------------
// K6 (MFMA): H = X @ W^T + fused alpha_s/alpha_d, split-bf16 (hi/lo).
// (unchanged — measured good in round 9)
// ---------------------------------------------------------------------------
template <int IN_DIM>
__global__ __launch_bounds__(256) void gemm_mfma_kernel(
    const float* __restrict__ X, const float* __restrict__ W,
    const float* __restrict__ a_src, const float* __restrict__ a_dst,
    float* __restrict__ H, float* __restrict__ AS, float* __restrict__ AD, int n) {
    constexpr int KT  = IN_DIM / 32;
    constexpr int LDB = IN_DIM + 8;
    __shared__ unsigned short sWhi[64 * LDB];
    __shared__ unsigned short sWlo[64 * LDB];
    int t = threadIdx.x;
    for (int idx = t; idx < 64 * IN_DIM; idx += 256) {
        int r = idx / IN_DIM, c = idx - r * IN_DIM;
        float w = W[idx];
        unsigned short hi = bf16rne(w);
        sWhi[r * LDB + c] = hi;
        sWlo[r * LDB + c] = bf16rne(w - bf16tof(hi));
    }
    __syncthreads();
    int lane = t & 63, wid = t >> 6;
    int l15 = lane & 15, l4 = lane >> 4;
    float asj[4], adj[4];
#pragma unroll
    for (int nt = 0; nt < 4; ++nt) {
        asj[nt] = a_src[nt * 16 + l15];
        adj[nt] = a_dst[nt * 16 + l15];
    }
    int gw = blockIdx.x * 4 + wid;
    int nw = gridDim.x * 4;
    int mtiles = n >> 4;
    for (int tile = gw; tile < mtiles; tile += nw) {
        int n0 = tile << 4;
        f32x4 acc[4];
#pragma unroll
        for (int nt = 0; nt < 4; ++nt) acc[nt] = f32x4{0.f, 0.f, 0.f, 0.f};
        const float* xbase = X + (size_t)(n0 + l15) * IN_DIM + l4 * 8;
#pragma unroll
        for (int kt = 0; kt < KT; ++kt) {
            float4 v0 = *reinterpret_cast<const float4*>(xbase + kt * 32);
            float4 v1 = *reinterpret_cast<const float4*>(xbase + kt * 32 + 4);
            float xv[8] = {v0.x, v0.y, v0.z, v0.w, v1.x, v1.y, v1.z, v1.w};
            short8 ahi, alo;
#pragma unroll
            for (int e = 0; e < 8; ++e) {
                unsigned short hb = bf16rne(xv[e]);
                ahi[e] = (short)hb;
                alo[e] = (short)bf16rne(xv[e] - bf16tof(hb));
            }
            int kcol = kt * 32 + l4 * 8;
#pragma unroll
            for (int nt = 0; nt < 4; ++nt) {
                short8 bhi = *reinterpret_cast<const short8*>(&sWhi[(nt * 16 + l15) * LDB + kcol]);
                short8 blo = *reinterpret_cast<const short8*>(&sWlo[(nt * 16 + l15) * LDB + kcol]);
                acc[nt] = __builtin_amdgcn_mfma_f32_16x16x32_bf16(ahi, bhi, acc[nt], 0, 0, 0);
                acc[nt] = __builtin_amdgcn_mfma_f32_16x16x32_bf16(ahi, blo, acc[nt], 0, 0, 0);
                acc[nt] = __builtin_amdgcn_mfma_f32_16x16x32_bf16(alo, bhi, acc[nt], 0, 0, 0);
            }
        }
        float c1[4] = {0.f, 0.f, 0.f, 0.f}, c2[4] = {0.f, 0.f, 0.f, 0.f};
#pragma unroll
        for (int nt = 0; nt < 4; ++nt) {
#pragma unroll
            for (int r = 0; r < 4; ++r) {
                float h = acc[nt][r];
                H[(size_t)(n0 + l4 * 4 + r) * 64 + nt * 16 + l15] = h;
                c1[r] += h * asj[nt];
                c2[r] += h * adj[nt];
            }
        }
#pragma unroll
        for (int r = 0; r < 4; ++r) {
#pragma unroll
            for (int d = 1; d < 16; d <<= 1) {
                c1[r] += __shfl_xor(c1[r], d, 64);
                c2[r] += __shfl_xor(c2[r], d, 64);
            }
            if (l15 == 0) {
                AS[n0 + l4 * 4 + r] = c1[r];
                AD[n0 + l4 * 4 + r] = c2[r];
            }
        }
    }
}

// ---------------------------------------------------------------------------
// K7: per-dst softmax + aggregation (unchanged — improved in round 11).
// ---------------------------------------------------------------------------
template <bool RELU>
__global__ __launch_bounds__(256) void aggregate_kernel(
    const float* __restrict__ AS, const float* __restrict__ AD,
    const float* __restrict__ H, const int* __restrict__ off,
    const int* __restrict__ csr, const float* __restrict__ bias,
    float* __restrict__ out, int n) {
    constexpr int CAP = 128;
    __shared__ float2 sEdge[4][CAP];
    int lane = threadIdx.x & 63, wid = threadIdx.x >> 6;
    int i = blockIdx.x * 4 + wid;
    if (i >= n) return;
    int s = off[i], e = off[i + 1];
    int deg = e - s;
    float ad = AD[i];
    float2* st = sEdge[wid];

    // Pass A
    float m = -1e30f, ssum = 0.f;
    for (int k = s + lane; k < e; k += 64) {
        int sc = csr[k];
        float ev = AS[sc] + ad;
        ev = ev > 0.f ? ev : NEG_SLOPE * ev;
        int idx = k - s;
        if (idx < CAP) st[idx] = make_float2(ev, __int_as_float(sc));
        float nm = fmaxf(m, ev);
        ssum = ssum * __expf(m - nm) + __expf(ev - nm);
        m = nm;
    }
#pragma unroll
    for (int d = 32; d >= 1; d >>= 1) {
        float om = __shfl_xor(m, d, 64);
        float os = __shfl_xor(ssum, d, 64);
        float nm = fmaxf(m, om);
        ssum = ssum * __expf(m - nm) + os * __expf(om - nm);
        m = nm;
    }
    float inv = 1.0f / ssum;

    asm volatile("s_waitcnt lgkmcnt(0)" ::: "memory");
    __builtin_amdgcn_sched_barrier(0);

    // Pass B
    float acc = 0.f;
    int lim = deg < CAP ? deg : CAP;
    int k2 = 0;
    for (; k2 + 4 <= lim; k2 += 4) {
        float2 e0 = st[k2 + 0];
        float2 e1 = st[k2 + 1];
        float2 e2 = st[k2 + 2];
        float2 e3 = st[k2 + 3];
        float v0 = H[(size_t)__float_as_int(e0.y) * 64 + lane];
        float v1 = H[(size_t)__float_as_int(e1.y) * 64 + lane];
        float v2 = H[(size_t)__float_as_int(e2.y) * 64 + lane];
        float v3 = H[(size_t)__float_as_int(e3.y) * 64 + lane];
        acc += __expf(e0.x - m) * v0;
        acc += __expf(e1.x - m) * v1;
        acc += __expf(e2.x - m) * v2;
        acc += __expf(e3.x - m) * v3;
    }
    for (; k2 < lim; ++k2) {
        float2 e0 = st[k2];
        acc += __expf(e0.x - m) * H[(size_t)__float_as_int(e0.y) * 64 + lane];
    }
    for (int k = s + CAP; k < e; ++k) {
        int sc = csr[k];
        float ev = AS[sc] + ad;
        ev = ev > 0.f ? ev : NEG_SLOPE * ev;
        acc += __expf(ev - m) * H[(size_t)sc * 64 + lane];
    }
    acc = acc * inv + bias[lane];
    if (RELU) acc = fmaxf(acc, 0.f);
    out[(size_t)i * 64 + lane] = acc;
}

// ---------------------------------------------------------------------------
extern "C" void kernel_launch(void* const* d_in, const int* in_sizes, int n_in,
                              void* d_out, int out_size, void* d_ws, size_t ws_size,
                              hipStream_t stream) {
    const float* x   = (const float*)d_in[0];
    const int*   ei  = (const int*)d_in[1];
    const float* W1  = (const float*)d_in[2];
    const float* a1s = (const float*)d_in[3];
    const float* a1d = (const float*)d_in[4];
    const float* b1  = (const float*)d_in[5];
    const float* W2  = (const float*)d_in[6];
    const float* a2s = (const float*)d_in[7];
    const float* a2d = (const float*)d_in[8];
    const float* b2  = (const float*)d_in[9];
    float* out = (float*)d_out;

    int n = in_sizes[0] / 128;
    int E = in_sizes[1] / 2;
    int ET = E + n;

    char* ws = (char*)d_ws;
    size_t o = 0;
    auto alloc = [&](size_t bytes) {
        void* p = ws + o;
        o += (bytes + 255) & ~(size_t)255;
        return p;
    };
    int*   flag   = (int*)alloc(4);
    int*   deg    = (int*)alloc((size_t)n * 4);
    int*   off    = (int*)alloc(((size_t)n + 1) * 4);
    int*   cursor = (int*)alloc((size_t)n * 4);
    int*   csr    = (int*)alloc((size_t)ET * 4);
    int*   bsum   = (int*)alloc(256 * 4);
    int*   total  = (int*)alloc(4);
    float* h1     = (float*)alloc((size_t)n * 64 * 4);
    float* as1    = (float*)alloc((size_t)n * 4);
    float* ad1    = (float*)alloc((size_t)n * 4);
    float* hr1    = (float*)alloc((size_t)n * 64 * 4);
    float* as2    = (float*)alloc((size_t)n * 4);
    float* ad2    = (float*)alloc((size_t)n * 4);
    (void)ws_size; (void)n_in; (void)out_size;

    int nb256 = (n + 255) / 256;
    int mtiles = n / 16;
    int gemm_blocks = (mtiles + 3) / 4;

    detect_kernel<<<1, 64, 0, stream>>>(ei, flag);
    init_deg_kernel<<<nb256, 256, 0, stream>>>(deg, n);
    count_kernel<<<2048, 256, 0, stream>>>(ei, E, n, deg, flag);
    scan1_kernel<<<nb256, 256, 0, stream>>>(deg, off, bsum, n);
    scan2_kernel<<<1, 256, 0, stream>>>(bsum, total, nb256);
    scan3_kernel<<<nb256, 256, 0, stream>>>(off, bsum, total, n);
    selfloop_kernel<<<nb256, 256, 0, stream>>>(off, cursor, csr, n);
    fill_kernel<<<2048, 256, 0, stream>>>(ei, E, n, cursor, csr, flag);

    // Layer 1
    gemm_mfma_kernel<128><<<gemm_blocks, 256, 0, stream>>>(x, W1, a1s, a1d, h1, as1, ad1, n);
    aggregate_kernel<true><<<(n + 3) / 4, 256, 0, stream>>>(as1, ad1, h1, off, csr, b1, hr1, n);

    // Layer 2 (reuse h1 as h2)
    gemm_mfma_kernel<64><<<gemm_blocks, 256, 0, stream>>>(hr1, W2, a2s, a2d, h1, as2, ad2, n);
    aggregate_kernel<false><<<(n + 3) / 4, 256, 0, stream>>>(as2, ad2, h1, off, csr, b2, out, n);
}

// Round 15
// 269.324 us; speedup vs baseline: 1.7591x; 1.0176x over previous
//
#include <hip/hip_runtime.h>
#include <cstdint>
#include <cstddef>

#ifndef NEG_SLOPE
#define NEG_SLOPE 0.2f
#endif

typedef __attribute__((ext_vector_type(8))) short short8;
typedef __attribute__((ext_vector_type(4))) float f32x4;

__device__ __forceinline__ unsigned short bf16rne(float f) {
    unsigned u = __builtin_bit_cast(unsigned, f);
    u += 0x7FFFu + ((u >> 16) & 1u);
    return (unsigned short)(u >> 16);
}
__device__ __forceinline__ float bf16tof(unsigned short h) {
    unsigned u = ((unsigned)h) << 16;
    return __builtin_bit_cast(float, u);
}

// ---------------------------------------------------------------------------
// K0: zero deg + detect int64/int32 edge storage (fused).
// ---------------------------------------------------------------------------
__global__ void init_kernel(const int* __restrict__ ei, int* __restrict__ flag,
                            int* __restrict__ deg, int n) {
    int i = blockIdx.x * blockDim.x + threadIdx.x;
    if (i < n) deg[i] = 0;
    if (i == 0) {
        int orv = 0;
#pragma unroll
        for (int k = 0; k < 16; ++k) orv |= ei[2 * k + 1];
        *flag = (orv == 0) ? 1 : 0;
    }
}

// ---------------------------------------------------------------------------
// K1 (fused): blocks [0,CB) = dst-partitioned degree count (XCD-local
// writes); blocks [CB,..) = layer-1 MFMA gemm. Independent work overlapped
// in one dispatch on the serial stream.
// ---------------------------------------------------------------------------
template <int IN_DIM>
__global__ __launch_bounds__(256) void count_gemm_kernel(
    const int* __restrict__ ei, int E, int n, int* __restrict__ deg,
    const int* __restrict__ flag, int CB,
    const float* __restrict__ X, const float* __restrict__ W,
    const float* __restrict__ a_src, const float* __restrict__ a_dst,
    float* __restrict__ H, float* __restrict__ AS, float* __restrict__ AD) {
    constexpr int KT  = IN_DIM / 32;
    constexpr int LDB = IN_DIM + 8;
    __shared__ unsigned short sWhi[64 * LDB];
    __shared__ unsigned short sWlo[64 * LDB];
    int bid = blockIdx.x;
    if (bid < CB) {
        // ---- count part (dst-partitioned by bid&7 -> XCD round-robin) ----
        int is64 = *flag;
        int part = bid & 7;
        int rank = bid >> 3;
        int nblk = CB >> 3;
        int step = (n + 7) >> 3;
        int lo = part * step;
        int hi = lo + step < n ? lo + step : n;
        int stride = nblk * blockDim.x;
        for (int e = rank * blockDim.x + threadIdx.x; e < E; e += stride) {
            int dst = is64 ? ei[2 * ((long)E + e)] : ei[E + e];
            if (dst >= lo && dst < hi) atomicAdd(&deg[dst], 1);
        }
        return;
    }
    // ---- gemm part ----
    int t = threadIdx.x;
    for (int idx = t; idx < 64 * IN_DIM; idx += 256) {
        int r = idx / IN_DIM, c = idx - r * IN_DIM;
        float w = W[idx];
        unsigned short hi = bf16rne(w);
        sWhi[r * LDB + c] = hi;
        sWlo[r * LDB + c] = bf16rne(w - bf16tof(hi));
    }
    __syncthreads();
    int lane = t & 63, wid = t >> 6;
    int l15 = lane & 15, l4 = lane >> 4;
    float asj[4], adj[4];
#pragma unroll
    for (int nt = 0; nt < 4; ++nt) {
        asj[nt] = a_src[nt * 16 + l15];
        adj[nt] = a_dst[nt * 16 + l15];
    }
    int gw = (bid - CB) * 4 + wid;
    int nw = (gridDim.x - CB) * 4;
    int mtiles = n >> 4;
    for (int tile = gw; tile < mtiles; tile += nw) {
        int n0 = tile << 4;
        f32x4 acc[4];
#pragma unroll
        for (int nt = 0; nt < 4; ++nt) acc[nt] = f32x4{0.f, 0.f, 0.f, 0.f};
        const float* xbase = X + (size_t)(n0 + l15) * IN_DIM + l4 * 8;
#pragma unroll
        for (int kt = 0; kt < KT; ++kt) {
            float4 v0 = *reinterpret_cast<const float4*>(xbase + kt * 32);
            float4 v1 = *reinterpret_cast<const float4*>(xbase + kt * 32 + 4);
            float xv[8] = {v0.x, v0.y, v0.z, v0.w, v1.x, v1.y, v1.z, v1.w};
            short8 ahi, alo;
#pragma unroll
            for (int e = 0; e < 8; ++e) {
                unsigned short hb = bf16rne(xv[e]);
                ahi[e] = (short)hb;
                alo[e] = (short)bf16rne(xv[e] - bf16tof(hb));
            }
            int kcol = kt * 32 + l4 * 8;
#pragma unroll
            for (int nt = 0; nt < 4; ++nt) {
                short8 bhi = *reinterpret_cast<const short8*>(&sWhi[(nt * 16 + l15) * LDB + kcol]);
                short8 blo = *reinterpret_cast<const short8*>(&sWlo[(nt * 16 + l15) * LDB + kcol]);
                acc[nt] = __builtin_amdgcn_mfma_f32_16x16x32_bf16(ahi, bhi, acc[nt], 0, 0, 0);
                acc[nt] = __builtin_amdgcn_mfma_f32_16x16x32_bf16(ahi, blo, acc[nt], 0, 0, 0);
                acc[nt] = __builtin_amdgcn_mfma_f32_16x16x32_bf16(alo, bhi, acc[nt], 0, 0, 0);
            }
        }
        float c1[4] = {0.f, 0.f, 0.f, 0.f}, c2[4] = {0.f, 0.f, 0.f, 0.f};
#pragma unroll
    for (int nt = 0; nt < 4; ++nt) {
#pragma unroll
            for (int r = 0; r < 4; ++r) {
                float h = acc[nt][r];
                H[(size_t)(n0 + l4 * 4 + r) * 64 + nt * 16 + l15] = h;
                c1[r] += h * asj[nt];
                c2[r] += h * adj[nt];
            }
        }
#pragma unroll
        for (int r = 0; r < 4; ++r) {
#pragma unroll
            for (int d = 1; d < 16; d <<= 1) {
                c1[r] += __shfl_xor(c1[r], d, 64);
                c2[r] += __shfl_xor(c2[r], d, 64);
            }
            if (l15 == 0) {
                AS[n0 + l4 * 4 + r] = c1[r];
                AD[n0 + l4 * 4 + r] = c2[r];
            }
        }
    }
}

// Standalone gemm (layer 2)
template <int IN_DIM>
__global__ __launch_bounds__(256) void gemm_mfma_kernel(
    const float* __restrict__ X, const float* __restrict__ W,
    const float* __restrict__ a_src, const float* __restrict__ a_dst,
    float* __restrict__ H, float* __restrict__ AS, float* __restrict__ AD, int n) {
    constexpr int KT  = IN_DIM / 32;
    constexpr int LDB = IN_DIM + 8;
    __shared__ unsigned short sWhi[64 * LDB];
    __shared__ unsigned short sWlo[64 * LDB];
    int t = threadIdx.x;
    for (int idx = t; idx < 64 * IN_DIM; idx += 256) {
        int r = idx / IN_DIM, c = idx - r * IN_DIM;
        float w = W[idx];
        unsigned short hi = bf16rne(w);
        sWhi[r * LDB + c] = hi;
        sWlo[r * LDB + c] = bf16rne(w - bf16tof(hi));
    }
    __syncthreads();
    int lane = t & 63, wid = t >> 6;
    int l15 = lane & 15, l4 = lane >> 4;
    float asj[4], adj[4];
#pragma unroll
    for (int nt = 0; nt < 4; ++nt) {
        asj[nt] = a_src[nt * 16 + l15];
        adj[nt] = a_dst[nt * 16 + l15];
    }
    int gw = blockIdx.x * 4 + wid;
    int nw = gridDim.x * 4;
    int mtiles = n >> 4;
    for (int tile = gw; tile < mtiles; tile += nw) {
        int n0 = tile << 4;
        f32x4 acc[4];
#pragma unroll
        for (int nt = 0; nt < 4; ++nt) acc[nt] = f32x4{0.f, 0.f, 0.f, 0.f};
        const float* xbase = X + (size_t)(n0 + l15) * IN_DIM + l4 * 8;
#pragma unroll
        for (int kt = 0; kt < KT; ++kt) {
            float4 v0 = *reinterpret_cast<const float4*>(xbase + kt * 32);
            float4 v1 = *reinterpret_cast<const float4*>(xbase + kt * 32 + 4);
            float xv[8] = {v0.x, v0.y, v0.z, v0.w, v1.x, v1.y, v1.z, v1.w};
            short8 ahi, alo;
#pragma unroll
            for (int e = 0; e < 8; ++e) {
                unsigned short hb = bf16rne(xv[e]);
                ahi[e] = (short)hb;
                alo[e] = (short)bf16rne(xv[e] - bf16tof(hb));
            }
            int kcol = kt * 32 + l4 * 8;
#pragma unroll
            for (int nt = 0; nt < 4; ++nt) {
                short8 bhi = *reinterpret_cast<const short8*>(&sWhi[(nt * 16 + l15) * LDB + kcol]);
                short8 blo = *reinterpret_cast<const short8*>(&sWlo[(nt * 16 + l15) * LDB + kcol]);
                acc[nt] = __builtin_amdgcn_mfma_f32_16x16x32_bf16(ahi, bhi, acc[nt], 0, 0, 0);
                acc[nt] = __builtin_amdgcn_mfma_f32_16x16x32_bf16(ahi, blo, acc[nt], 0, 0, 0);
                acc[nt] = __builtin_amdgcn_mfma_f32_16x16x32_bf16(alo, bhi, acc[nt], 0, 0, 0);
            }
        }
        float c1[4] = {0.f, 0.f, 0.f, 0.f}, c2[4] = {0.f, 0.f, 0.f, 0.f};
#pragma unroll
        for (int nt = 0; nt < 4; ++nt) {
#pragma unroll
            for (int r = 0; r < 4; ++r) {
                float h = acc[nt][r];
                H[(size_t)(n0 + l4 * 4 + r) * 64 + nt * 16 + l15] = h;
                c1[r] += h * asj[nt];
                c2[r] += h * adj[nt];
            }
        }
#pragma unroll
        for (int r = 0; r < 4; ++r) {
#pragma unroll
            for (int d = 1; d < 16; d <<= 1) {
                c1[r] += __shfl_xor(c1[r], d, 64);
                c2[r] += __shfl_xor(c2[r], d, 64);
            }
            if (l15 == 0) {
                AS[n0 + l4 * 4 + r] = c1[r];
                AD[n0 + l4 * 4 + r] = c2[r];
            }
        }
    }
}

// ---------------------------------------------------------------------------
// K3a/b: multi-block exclusive scan. scan1 adds +1/node (self-loop).
// ---------------------------------------------------------------------------
__global__ __launch_bounds__(256) void scan1_kernel(const int* __restrict__ deg,
                                                    int* __restrict__ off,
                                                    int* __restrict__ bsum, int n) {
    __shared__ int ws[4];
    int t = threadIdx.x, lane = t & 63, w = t >> 6;
    int idx = blockIdx.x * 256 + t;
    int v = (idx < n) ? deg[idx] + 1 : 0;   // +1 self-loop
    int inc = v;
#pragma unroll
    for (int d = 1; d < 64; d <<= 1) {
        int o = __shfl_up(inc, d, 64);
        if (lane >= d) inc += o;
    }
    if (lane == 63) ws[w] = inc;
    __syncthreads();
    int wpre = 0;
    for (int x = 0; x < w; ++x) wpre += ws[x];
    if (idx < n) off[idx] = wpre + inc - v;
    if (t == 255) bsum[blockIdx.x] = wpre + inc;
}

__global__ __launch_bounds__(256) void scan2_kernel(int* __restrict__ bsum,
                                                    int* __restrict__ total, int nb) {
    __shared__ int ws[4];
    int t = threadIdx.x, lane = t & 63, w = t >> 6;
    int v = (t < nb) ? bsum[t] : 0;
    int inc = v;
#pragma unroll
    for (int d = 1; d < 64; d <<= 1) {
        int o = __shfl_up(inc, d, 64);
        if (lane >= d) inc += o;
    }
    if (lane == 63) ws[w] = inc;
    __syncthreads();
    int wpre = 0;
    for (int x = 0; x < w; ++x) wpre += ws[x];
    if (t < nb) bsum[t] = wpre + inc - v;
    if (t == 255) *total = wpre + inc;
}

// K3c (fused with selfloop): finalize off, plant self-loop, init cursor.
__global__ __launch_bounds__(256) void scan3_selfloop_kernel(
    int* __restrict__ off, const int* __restrict__ bsum,
    const int* __restrict__ total, int* __restrict__ cursor,
    int* __restrict__ csr, int n) {
    int idx = blockIdx.x * 256 + threadIdx.x;
    if (idx < n) {
        int o = off[idx] + bsum[blockIdx.x];
        off[idx] = o;
        csr[o] = idx;
        cursor[idx] = o + 1;
    }
    if (idx == 0) off[n] = *total;
}

// ---------------------------------------------------------------------------
// K5: dst-partitioned CSR scatter (unchanged — measured good in round 12).
// ---------------------------------------------------------------------------
__global__ void fill_kernel(const int* __restrict__ ei, int E, int n,
                            int* __restrict__ cursor, int* __restrict__ csr,
                            const int* __restrict__ flag) {
    int is64 = *flag;
    int part = blockIdx.x & 7;
    int rank = blockIdx.x >> 3;
    int nblk = gridDim.x >> 3;
    int step = (n + 7) >> 3;
    int lo = part * step;
    int hi = lo + step < n ? lo + step : n;
    int stride = nblk * blockDim.x;
    for (int e = rank * blockDim.x + threadIdx.x; e < E; e += stride) {
        int dst = is64 ? ei[2 * ((long)E + e)] : ei[E + e];
        if (dst >= lo && dst < hi) {
            int src = is64 ? ei[2 * (long)e] : ei[e];
            int slot = atomicAdd(&cursor[dst], 1);
            csr[slot] = src;
        }
    }
}

// ---------------------------------------------------------------------------
// K7: per-dst softmax + aggregation, one wave per node, NO max-shift
// (|e| <= ~3 in practice, <= ~8 worst-case -> exp safely in fp32 range;
// softmax is shift-invariant so result matches reference). Pass A stashes
// p=exp(e) directly; Pass B is exp-free.
// ---------------------------------------------------------------------------
template <bool RELU>
__global__ __launch_bounds__(256) void aggregate_kernel(
    const float* __restrict__ AS, const float* __restrict__ AD,
    const float* __restrict__ H, const int* __restrict__ off,
    const int* __restrict__ csr, const float* __restrict__ bias,
    float* __restrict__ out, int n) {
    constexpr int CAP = 128;
    __shared__ float2 sEdge[4][CAP];
    int lane = threadIdx.x & 63, wid = threadIdx.x >> 6;
    int i = blockIdx.x * 4 + wid;
    if (i >= n) return;
    int s = off[i], e = off[i + 1];
    int deg = e - s;
    float ad = AD[i];
    float2* st = sEdge[wid];

    // Pass A: p = exp(leakyrelu(e)), stash (p, src), sum
    float ssum = 0.f;
    for (int k = s + lane; k < e; k += 64) {
        int sc = csr[k];
        float ev = AS[sc] + ad;
        ev = ev > 0.f ? ev : NEG_SLOPE * ev;
        float p = __expf(ev);
        int idx = k - s;
        if (idx < CAP) st[idx] = make_float2(p, __int_as_float(sc));
        ssum += p;
    }
#pragma unroll
    for (int d = 32; d >= 1; d >>= 1) ssum += __shfl_xor(ssum, d, 64);
    float inv = 1.0f / ssum;

    asm volatile("s_waitcnt lgkmcnt(0)" ::: "memory");
    __builtin_amdgcn_sched_barrier(0);

    // Pass B: exp-free gather, 4-way unrolled for MLP
    float acc = 0.f;
    int lim = deg < CAP ? deg : CAP;
    int k2 = 0;
    for (; k2 + 4 <= lim; k2 += 4) {
        float2 e0 = st[k2 + 0];
        float2 e1 = st[k2 + 1];
        float2 e2 = st[k2 + 2];
        float2 e3 = st[k2 + 3];
        float v0 = H[(size_t)__float_as_int(e0.y) * 64 + lane];
        float v1 = H[(size_t)__float_as_int(e1.y) * 64 + lane];
        float v2 = H[(size_t)__float_as_int(e2.y) * 64 + lane];
        float v3 = H[(size_t)__float_as_int(e3.y) * 64 + lane];
        acc += e0.x * v0;
        acc += e1.x * v1;
        acc += e2.x * v2;
        acc += e3.x * v3;
    }
    for (; k2 < lim; ++k2) {
        float2 e0 = st[k2];
        acc += e0.x * H[(size_t)__float_as_int(e0.y) * 64 + lane];
    }
    for (int k = s + CAP; k < e; ++k) {   // deg > CAP fallback (uniform)
        int sc = csr[k];
        float ev = AS[sc] + ad;
        ev = ev > 0.f ? ev : NEG_SLOPE * ev;
        acc += __expf(ev) * H[(size_t)sc * 64 + lane];
    }
    acc = acc * inv + bias[lane];
    if (RELU) acc = fmaxf(acc, 0.f);
    out[(size_t)i * 64 + lane] = acc;
}

// ---------------------------------------------------------------------------
extern "C" void kernel_launch(void* const* d_in, const int* in_sizes, int n_in,
                              void* d_out, int out_size, void* d_ws, size_t ws_size,
                              hipStream_t stream) {
    const float* x   = (const float*)d_in[0];
    const int*   ei  = (const int*)d_in[1];
    const float* W1  = (const float*)d_in[2];
    const float* a1s = (const float*)d_in[3];
    const float* a1d = (const float*)d_in[4];
    const float* b1  = (const float*)d_in[5];
    const float* W2  = (const float*)d_in[6];
    const float* a2s = (const float*)d_in[7];
    const float* a2d = (const float*)d_in[8];
    const float* b2  = (const float*)d_in[9];
    float* out = (float*)d_out;

    int n = in_sizes[0] / 128;
    int E = in_sizes[1] / 2;
    int ET = E + n;

    char* ws = (char*)d_ws;
    size_t o = 0;
    auto alloc = [&](size_t bytes) {
        void* p = ws + o;
        o += (bytes + 255) & ~(size_t)255;
        return p;
    };
    int*   flag   = (int*)alloc(4);
    int*   deg    = (int*)alloc((size_t)n * 4);
    int*   off    = (int*)alloc(((size_t)n + 1) * 4);
    int*   cursor = (int*)alloc((size_t)n * 4);
    int*   csr    = (int*)alloc((size_t)ET * 4);
    int*   bsum   = (int*)alloc(256 * 4);
    int*   total  = (int*)alloc(4);
    float* h1     = (float*)alloc((size_t)n * 64 * 4);
    float* as1    = (float*)alloc((size_t)n * 4);
    float* ad1    = (float*)alloc((size_t)n * 4);
    float* hr1    = (float*)alloc((size_t)n * 64 * 4);
    float* as2    = (float*)alloc((size_t)n * 4);
    float* ad2    = (float*)alloc((size_t)n * 4);
    (void)ws_size; (void)n_in; (void)out_size;

    int nb256 = (n + 255) / 256;
    int mtiles = n / 16;
    int gemm_blocks = (mtiles + 3) / 4;
    const int CB = 2048;                       // count blocks (mult of 8)

    init_kernel<<<nb256, 256, 0, stream>>>(ei, flag, deg, n);
    count_gemm_kernel<128><<<CB + gemm_blocks, 256, 0, stream>>>(
        ei, E, n, deg, flag, CB, x, W1, a1s, a1d, h1, as1, ad1);
    scan1_kernel<<<nb256, 256, 0, stream>>>(deg, off, bsum, n);
    scan2_kernel<<<1, 256, 0, stream>>>(bsum, total, nb256);
    scan3_selfloop_kernel<<<nb256, 256, 0, stream>>>(off, bsum, total, cursor, csr, n);
    fill_kernel<<<2048, 256, 0, stream>>>(ei, E, n, cursor, csr, flag);

    aggregate_kernel<true><<<(n + 3) / 4, 256, 0, stream>>>(as1, ad1, h1, off, csr, b1, hr1, n);
    gemm_mfma_kernel<64><<<gemm_blocks, 256, 0, stream>>>(hr1, W2, a2s, a2d, h1, as2, ad2, n);
    aggregate_kernel<false><<<(n + 3) / 4, 256, 0, stream>>>(as2, ad2, h1, off, csr, b2, out, n);
}